// Round 11
// baseline (232.713 us; speedup 1.0000x reference)
//
#include <hip/hip_runtime.h>
#include <hip/hip_fp8.h>
#include <math.h>

typedef __bf16 bf16x8 __attribute__((ext_vector_type(8)));
typedef __bf16 bf16x4 __attribute__((ext_vector_type(4)));
typedef float  f32x4  __attribute__((ext_vector_type(4)));
typedef float  f32x16 __attribute__((ext_vector_type(16)));
typedef long   i64x2  __attribute__((ext_vector_type(2)));   // 16B, 16B-aligned

#define QL    32
#define DL    256
#define DIM   256
#define NK    21
#define KSOFT 20
#define STR   264                 // bf16 LDS row stride (mono fallback)
#define STR8  272                 // fp8 LDS row stride in BYTES (256+16, 16B-aligned rows)
#define L2E   1.4426950408889634f

#if __has_builtin(__builtin_amdgcn_exp2f)
#define EXP2F(x) __builtin_amdgcn_exp2f(x)
#else
#define EXP2F(x) exp2f(x)
#endif

// float pair -> packed OCP e4m3 pair (low 16 bits). gfx950 HW conversion.
static __device__ inline unsigned cvt2_e4m3(float a, float b)
{
#if __has_builtin(__builtin_amdgcn_cvt_pk_fp8_f32)
    return (unsigned)__builtin_amdgcn_cvt_pk_fp8_f32(a, b, 0, false) & 0xFFFFu;
#else
    __hip_fp8_e4m3 fa(a), fb(b);
    return (unsigned)fa.__x | ((unsigned)fb.__x << 8);
#endif
}

// Gaussian soft bins, anchored geometric recurrence:
//   E_k = exp(-50 (mm - mu_k)^2), mu_k = -0.95 + 0.1k
//   E_{k+1} = E_k * U * e^{-k},   U = e^{10 mm + 9}
// Anchors at k = 0, 7, 14 (spans <= 6 steps). Underflowed anchors only zero
// terms whose true value < 1e-38 -> negligible in Sqk sums.
#define EVAL_BINS(mm, ACC0)                                                  \
    {                                                                        \
        float U  = EXP2F(L2E * fmaf(10.0f, (mm), 9.0f));                     \
        float t0 = (mm) + 0.95f;                                             \
        float E  = EXP2F((-50.0f * L2E) * t0 * t0);                          \
        ACC0[0] += E;                                                        \
        E *= U;                           ACC0[1]  += E; /* e^-0  */         \
        E *= U * 0.36787944117144233f;    ACC0[2]  += E; /* e^-1  */         \
        E *= U * 0.1353352832366127f;     ACC0[3]  += E; /* e^-2  */         \
        E *= U * 0.049787068367863944f;   ACC0[4]  += E; /* e^-3  */         \
        E *= U * 0.018315638888734179f;   ACC0[5]  += E; /* e^-4  */         \
        E *= U * 0.006737946999085467f;   ACC0[6]  += E; /* e^-5  */         \
        float t7 = (mm) + 0.25f;                                             \
        E = EXP2F((-50.0f * L2E) * t7 * t7);                                 \
        ACC0[7] += E;                                                        \
        E *= U * 0.0009118819655545162f;  ACC0[8]  += E; /* e^-7  */         \
        E *= U * 0.00033546262790251185f; ACC0[9]  += E; /* e^-8  */         \
        E *= U * 0.0001234098040866796f;  ACC0[10] += E; /* e^-9  */         \
        E *= U * 4.5399929762484854e-05f; ACC0[11] += E; /* e^-10 */         \
        E *= U * 1.670170079024566e-05f;  ACC0[12] += E; /* e^-11 */         \
        E *= U * 6.14421235332821e-06f;   ACC0[13] += E; /* e^-12 */         \
        float t14 = (mm) - 0.45f;                                            \
        E = EXP2F((-50.0f * L2E) * t14 * t14);                               \
        ACC0[14] += E;                                                       \
        E *= U * 8.315287191035679e-07f;  ACC0[15] += E; /* e^-14 */         \
        E *= U * 3.059023205018258e-07f;  ACC0[16] += E; /* e^-15 */         \
        E *= U * 1.1253517471925912e-07f; ACC0[17] += E; /* e^-16 */         \
        E *= U * 4.139937718785167e-08f;  ACC0[18] += E; /* e^-17 */         \
        E *= U * 1.522997974471263e-08f;  ACC0[19] += E; /* e^-18 */         \
    }

// ---------- Phase 1: normalize emb rows -> fp8 e4m3 table (scaled x16) -------
// Also zeroes the per-b completion tickets used by the fused finale.
__global__ __launch_bounds__(256)
void knrm_prep8(const float* __restrict__ emb, unsigned char* __restrict__ tab,
                int V, int* __restrict__ tick, int B)
{
    {
        int idx = blockIdx.x * 256 + threadIdx.x;
        if (idx < B) tick[idx] = 0;
    }
    const int wave = threadIdx.x >> 6;
    const int lane = threadIdx.x & 63;
    const int row0 = (blockIdx.x * 4 + wave) * 2;
    if (row0 >= V) return;                     // V even -> row0+1 also valid

    float4 a = reinterpret_cast<const float4*>(emb + (size_t)row0 * DIM)[lane];
    float4 c = reinterpret_cast<const float4*>(emb + (size_t)(row0 + 1) * DIM)[lane];
    float sa = a.x*a.x + a.y*a.y + a.z*a.z + a.w*a.w;
    float sc = c.x*c.x + c.y*c.y + c.z*c.z + c.w*c.w;
    #pragma unroll
    for (int m = 32; m; m >>= 1) { sa += __shfl_xor(sa, m); sc += __shfl_xor(sc, m); }
    float ia = rsqrtf(fmaxf(sa, 1e-16f)) * 16.0f;   // x16 pre-scale
    float ic = rsqrtf(fmaxf(sc, 1e-16f)) * 16.0f;
    unsigned pa = cvt2_e4m3(a.x * ia, a.y * ia) | (cvt2_e4m3(a.z * ia, a.w * ia) << 16);
    unsigned pc = cvt2_e4m3(c.x * ic, c.y * ic) | (cvt2_e4m3(c.z * ic, c.w * ic) << 16);
    *reinterpret_cast<unsigned*>(tab + (size_t)row0 * 256 + lane * 4) = pa;
    *reinterpret_cast<unsigned*>(tab + (size_t)(row0 + 1) * 256 + lane * 4) = pc;
}

// ---------- Phase 2: mainD (best measured, <59.2us) + fused finale -----------
// mainD's K-permuted dwordx4 gathers are the one lever with a confirmed
// positive delta (mainB 63.6 -> mainD <59.2). mainE's 45.5KB LDS dropped
// residency to 3 blocks/CU (grid needs 4) -> 4/3 two-pass elongation (72-80us)
// -> reverted. LDS here is 12.8KB (>=8 blocks/CU capacity, single pass).
// K-permutation: lane (l31,hw) loads row*256 + j*32 + hw*16 as dwordx4; call
// (j,t) uses the t-th 8B half on BOTH operands (exact for a dot product).
// Finale fused via per-b ticket: saves the knrm_final launch + gap.
// C layout (verified, shape-determined): col=lane&31 (fixed q row -> acc[21]
// off the fragment), row=(reg&3)+8*(reg>>2)+4*(lane>>5).
__global__ __launch_bounds__(256, 2)
void knrm_mainD(const int* __restrict__ q1t, const int* __restrict__ d1t,
                const int* __restrict__ q2t, const int* __restrict__ d2t,
                const unsigned char* __restrict__ tab,
                const float* __restrict__ W0, const float* __restrict__ b0,
                const float* __restrict__ W1, const float* __restrict__ b1,
                const float* __restrict__ W2, const float* __restrict__ b2,
                float* __restrict__ lg, int* __restrict__ tick,
                float* __restrict__ out, int B)
{
    const int b    = blockIdx.x;
    const int pair = blockIdx.y;
    const int tid  = threadIdx.x;
    const int wave = tid >> 6;
    const int lane = tid & 63;
    const int l31  = lane & 31;    // A row within tile / C col (q row)
    const int hw   = lane >> 5;    // k-slice selector

    const int* qtok = pair ? q2t : q1t;
    const int* dtok = pair ? d2t : d1t;

    __shared__ __align__(16) unsigned char qbuf[QL * STR8];   // 8.5 KB
    __shared__ float Sqk[QL * NK];
    __shared__ int   dtok_s[DL];
    __shared__ float km[NK];
    __shared__ float h0[10];
    __shared__ float h1[5];

    // eval needs the doc tokens; gathers read their own tokens directly.
    dtok_s[tid] = dtok[b * DL + tid];
    for (int e = tid; e < QL * NK; e += 256) Sqk[e] = 0.0f;
    if (tid < NK) km[tid] = 0.0f;

    // ---- issue ALL doc gathers first (tokens direct from global, coalesced)
    const int tok0 = dtok[b * DL + wave * 64 + l31];
    const int tok1 = dtok[b * DL + wave * 64 + 32 + l31];
    const unsigned char* a0 = tab + (size_t)tok0 * 256 + hw * 16;
    const unsigned char* a1 = tab + (size_t)tok1 * 256 + hw * 16;
    i64x2 af0[8], af1[8];
    #pragma unroll
    for (int j = 0; j < 8; ++j)
        af0[j] = *reinterpret_cast<const i64x2*>(a0 + j * 32);
    #pragma unroll
    for (int j = 0; j < 8; ++j)
        af1[j] = *reinterpret_cast<const i64x2*>(a1 + j * 32);

    // ---- stage 32 q rows (coalesced: 2 rows per 8B-lane instr per wave)
    {
        long qv[4];
        #pragma unroll
        for (int i = 0; i < 4; ++i) {
            int r = wave * 8 + i * 2 + hw;
            qv[i] = *reinterpret_cast<const long*>(
                tab + (size_t)qtok[b * QL + r] * 256 + l31 * 8);
        }
        #pragma unroll
        for (int i = 0; i < 4; ++i) {
            int r = wave * 8 + i * 2 + hw;
            *reinterpret_cast<long*>(&qbuf[r * STR8 + l31 * 8]) = qv[i];
        }
    }
    __syncthreads();   // qbuf + dtok_s + Sqk visible; LAST barrier before flush

    const int qtk1 = qtok[b * QL + l31];   // this lane's q token (C col fixed)
    const unsigned char* qrd = &qbuf[l31 * STR8 + hw * 16];

    float acc[NK];
    #pragma unroll
    for (int k = 0; k < NK; ++k) acc[k] = 0.0f;

    // ================= tile 0: docs [wave*64, +32) =================
    {
        f32x16 mc;
        #pragma unroll
        for (int j = 0; j < 16; ++j) mc[j] = 0.0f;
        #pragma unroll
        for (int j = 0; j < 8; ++j) {
            i64x2 qd = *reinterpret_cast<const i64x2*>(qrd + j * 32);
            mc = __builtin_amdgcn_mfma_f32_32x32x16_fp8_fp8(af0[j].x, qd.x, mc, 0, 0, 0);
            mc = __builtin_amdgcn_mfma_f32_32x32x16_fp8_fp8(af0[j].y, qd.y, mc, 0, 0, 0);
        }
        const int dbase = wave * 64;
        #pragma unroll
        for (int r = 0; r < 16; ++r) {
            float mm = mc[r] * 0.00390625f;      // undo x16*x16 scale
            EVAL_BINS(mm, acc);
            int crow = dbase + (r & 3) + 8 * (r >> 2) + 4 * hw;
            acc[KSOFT] += (dtok_s[crow] == qtk1) ? 1.0f : 0.0f;
        }
    }
    // ================= tile 1: docs [wave*64+32, +32) ==============
    {
        f32x16 mc;
        #pragma unroll
        for (int j = 0; j < 16; ++j) mc[j] = 0.0f;
        #pragma unroll
        for (int j = 0; j < 8; ++j) {
            i64x2 qd = *reinterpret_cast<const i64x2*>(qrd + j * 32);
            mc = __builtin_amdgcn_mfma_f32_32x32x16_fp8_fp8(af1[j].x, qd.x, mc, 0, 0, 0);
            mc = __builtin_amdgcn_mfma_f32_32x32x16_fp8_fp8(af1[j].y, qd.y, mc, 0, 0, 0);
        }
        const int dbase = wave * 64 + 32;
        #pragma unroll
        for (int r = 0; r < 16; ++r) {
            float mm = mc[r] * 0.00390625f;
            EVAL_BINS(mm, acc);
            int crow = dbase + (r & 3) + 8 * (r >> 2) + 4 * hw;
            acc[KSOFT] += (dtok_s[crow] == qtk1) ? 1.0f : 0.0f;
        }
    }

    // ---- flush: 8 lanes (2 half-waves x 4 doc-waves) merge per q-row
    #pragma unroll
    for (int k = 0; k < NK; ++k)
        atomicAdd(&Sqk[l31 * NK + k], acc[k]);
    __syncthreads();

    // ---- km[k] = sum_q log1p(Sqk[q][k])
    for (int e = tid; e < QL * NK; e += 256)
        atomicAdd(&km[e % NK], log1pf(Sqk[e]));
    __syncthreads();

    // ---- tiny MLP 21 -> 10 -> 5 -> 1
    if (tid < 10) {
        float h = b0[tid];
        #pragma unroll
        for (int k = 0; k < NK; ++k) h = fmaf(km[k], W0[tid*NK + k], h);
        h0[tid] = fmaxf(h, 0.0f);
    }
    __syncthreads();
    if (tid < 5) {
        float h = b1[tid];
        #pragma unroll
        for (int j = 0; j < 10; ++j) h = fmaf(h0[j], W1[tid*10 + j], h);
        h1[tid] = fmaxf(h, 0.0f);
    }
    __syncthreads();
    if (tid == 0) {
        float l = b2[0];
        #pragma unroll
        for (int j = 0; j < 5; ++j) l = fmaf(h1[j], W2[j], l);
        lg[pair * B + b] = l;
        // ---- fused finale: last (b,*) block computes the sigmoid
        __threadfence();
        int old = atomicAdd(&tick[b], 1);
        if (old == 1) {
            __threadfence();
            float z = lg[b] - lg[B + b];
            out[b] = 1.0f / (1.0f + expf(-z));
        }
    }
}

// ---------- Fallback (monolithic): only if ws can't hold the fp8 table -------
__global__ __launch_bounds__(256, 2)
void knrm_mono(const int* __restrict__ q1t, const int* __restrict__ d1t,
               const int* __restrict__ q2t, const int* __restrict__ d2t,
               const float* __restrict__ emb,
               const float* __restrict__ W0, const float* __restrict__ b0,
               const float* __restrict__ W1, const float* __restrict__ b1,
               const float* __restrict__ W2, const float* __restrict__ b2,
               float* __restrict__ out)
{
    const int b    = blockIdx.x;
    const int tid  = threadIdx.x;
    const int wave = tid >> 6;
    const int lane = tid & 63;
    const int qt   = wave >> 1;
    const int dt   = wave & 1;
    const int g    = lane >> 4;
    const int cl   = lane & 15;

    __shared__ __align__(16) __bf16 qbuf[QL * STR];
    __shared__ __align__(16) __bf16 dbuf[32 * STR];
    __shared__ float Sqk[QL * NK];
    __shared__ int   dtok_s[DL];
    __shared__ int   qtok_s[QL];
    __shared__ float km[NK];
    __shared__ float h0[10];
    __shared__ float h1[5];
    __shared__ float logit[2];

    for (int pair = 0; pair < 2; ++pair) {
        const int* qtok = pair ? q2t : q1t;
        const int* dtok = pair ? d2t : d1t;

        if (tid < QL) qtok_s[tid] = qtok[b * QL + tid];
        dtok_s[tid] = dtok[b * DL + tid];
        for (int e = tid; e < QL * NK; e += 256) Sqk[e] = 0.0f;
        if (tid < NK) km[tid] = 0.0f;
        __syncthreads();

        #pragma unroll
        for (int i = 0; i < 8; ++i) {
            int row = wave * 8 + i;
            int tok = qtok_s[row];
            float4 v = reinterpret_cast<const float4*>(emb + (size_t)tok * DIM)[lane];
            float s = v.x*v.x + v.y*v.y + v.z*v.z + v.w*v.w;
            #pragma unroll
            for (int m = 32; m; m >>= 1) s += __shfl_xor(s, m);
            float inv = rsqrtf(fmaxf(s, 1e-16f));
            bf16x4 o;
            o[0] = (__bf16)(v.x * inv); o[1] = (__bf16)(v.y * inv);
            o[2] = (__bf16)(v.z * inv); o[3] = (__bf16)(v.w * inv);
            *reinterpret_cast<bf16x4*>(&qbuf[row * STR + lane * 4]) = o;
        }

        int qtk[4];
        #pragma unroll
        for (int i = 0; i < 4; ++i) qtk[i] = qtok_s[qt * 16 + g * 4 + i];

        float acc[4 * NK];
        #pragma unroll
        for (int e = 0; e < 4 * NK; ++e) acc[e] = 0.0f;

        for (int tile = 0; tile < 8; ++tile) {
            #pragma unroll
            for (int i = 0; i < 8; ++i) {
                int r = wave * 8 + i;
                int tok = dtok_s[tile * 32 + r];
                float4 v = reinterpret_cast<const float4*>(emb + (size_t)tok * DIM)[lane];
                float s = v.x*v.x + v.y*v.y + v.z*v.z + v.w*v.w;
                #pragma unroll
                for (int m = 32; m; m >>= 1) s += __shfl_xor(s, m);
                float inv = rsqrtf(fmaxf(s, 1e-16f));
                bf16x4 o;
                o[0] = (__bf16)(v.x * inv); o[1] = (__bf16)(v.y * inv);
                o[2] = (__bf16)(v.z * inv); o[3] = (__bf16)(v.w * inv);
                *reinterpret_cast<bf16x4*>(&dbuf[r * STR + lane * 4]) = o;
            }
            __syncthreads();

            f32x4 cf = {0.0f, 0.0f, 0.0f, 0.0f};
            #pragma unroll
            for (int ks = 0; ks < 8; ++ks) {
                bf16x8 af  = *reinterpret_cast<const bf16x8*>(&qbuf[(qt*16 + cl)*STR + ks*32 + g*8]);
                bf16x8 bfr = *reinterpret_cast<const bf16x8*>(&dbuf[(dt*16 + cl)*STR + ks*32 + g*8]);
                cf = __builtin_amdgcn_mfma_f32_16x16x32_bf16(af, bfr, cf, 0, 0, 0);
            }

            int dtk = dtok_s[tile*32 + dt*16 + cl];
            #pragma unroll
            for (int i = 0; i < 4; ++i) {
                float mm = cf[i];
                float* a4 = &acc[i*NK];
                EVAL_BINS(mm, a4);
                a4[KSOFT] += (dtk == qtk[i]) ? 1.0f : 0.0f;
            }
            __syncthreads();
        }

        #pragma unroll
        for (int i = 0; i < 4; ++i) {
            int row = qt*16 + g*4 + i;
            #pragma unroll
            for (int k = 0; k < NK; ++k)
                atomicAdd(&Sqk[row*NK + k], acc[i*NK + k]);
        }
        __syncthreads();

        for (int e = tid; e < QL * NK; e += 256)
            atomicAdd(&km[e % NK], log1pf(Sqk[e]));
        __syncthreads();

        if (tid < 10) {
            float h = b0[tid];
            #pragma unroll
            for (int k = 0; k < NK; ++k) h = fmaf(km[k], W0[tid*NK + k], h);
            h0[tid] = fmaxf(h, 0.0f);
        }
        __syncthreads();
        if (tid < 5) {
            float h = b1[tid];
            #pragma unroll
            for (int j = 0; j < 10; ++j) h = fmaf(h0[j], W1[tid*10 + j], h);
            h1[tid] = fmaxf(h, 0.0f);
        }
        __syncthreads();
        if (tid == 0) {
            float l = b2[0];
            #pragma unroll
            for (int j = 0; j < 5; ++j) l = fmaf(h1[j], W2[j], l);
            logit[pair] = l;
        }
        __syncthreads();
    }

    if (tid == 0) {
        float z = logit[0] - logit[1];
        out[b] = 1.0f / (1.0f + expf(-z));
    }
}

extern "C" void kernel_launch(void* const* d_in, const int* in_sizes, int n_in,
                              void* d_out, int out_size, void* d_ws, size_t ws_size,
                              hipStream_t stream) {
    const int*   q1  = (const int*)d_in[0];
    const int*   d1  = (const int*)d_in[1];
    const int*   q2  = (const int*)d_in[2];
    const int*   d2  = (const int*)d_in[3];
    const float* emb = (const float*)d_in[4];
    const float* W0  = (const float*)d_in[5];
    const float* b0  = (const float*)d_in[6];
    const float* W1  = (const float*)d_in[7];
    const float* b1  = (const float*)d_in[8];
    const float* W2  = (const float*)d_in[9];
    const float* b2  = (const float*)d_in[10];
    float* out = (float*)d_out;

    const int B = in_sizes[0] / QL;       // 512
    const int V = in_sizes[4] / DIM;      // 100000

    size_t tab_bytes = (size_t)V * 256;   // fp8 table
    size_t lg_off    = (tab_bytes + 255) & ~(size_t)255;
    size_t tick_off  = lg_off + (((size_t)2 * B * sizeof(float) + 255) & ~(size_t)255);
    size_t need      = tick_off + (size_t)B * sizeof(int);

    if (ws_size >= need) {
        unsigned char* tab = (unsigned char*)d_ws;
        float* lg   = (float*)((char*)d_ws + lg_off);
        int*   tick = (int*)((char*)d_ws + tick_off);

        knrm_prep8<<<(V/2 + 3) / 4, 256, 0, stream>>>(emb, tab, V, tick, B);
        dim3 grid(B, 2);
        knrm_mainD<<<grid, 256, 0, stream>>>(q1, d1, q2, d2, tab,
                                             W0, b0, W1, b1, W2, b2,
                                             lg, tick, out, B);
    } else {
        knrm_mono<<<B, 256, 0, stream>>>(q1, d1, q2, d2, emb,
                                         W0, b0, W1, b1, W2, b2, out);
    }
}

// Round 12
// 225.190 us; speedup vs baseline: 1.0334x; 1.0334x over previous
//
#include <hip/hip_runtime.h>
#include <hip/hip_fp8.h>
#include <math.h>

typedef __bf16 bf16x8 __attribute__((ext_vector_type(8)));
typedef __bf16 bf16x4 __attribute__((ext_vector_type(4)));
typedef float  f32x4  __attribute__((ext_vector_type(4)));
typedef float  f32x16 __attribute__((ext_vector_type(16)));
typedef long   i64x2  __attribute__((ext_vector_type(2)));   // 16B, 16B-aligned

#define QL    32
#define DL    256
#define DIM   256
#define NK    21
#define KSOFT 20
#define STR   264                 // bf16 LDS row stride (mono fallback)
#define STR8  272                 // fp8 LDS row stride in BYTES (256+16, 16B-aligned rows)
#define L2E   1.4426950408889634f

#if __has_builtin(__builtin_amdgcn_exp2f)
#define EXP2F(x) __builtin_amdgcn_exp2f(x)
#else
#define EXP2F(x) exp2f(x)
#endif

// float pair -> packed OCP e4m3 pair (low 16 bits). gfx950 HW conversion.
static __device__ inline unsigned cvt2_e4m3(float a, float b)
{
#if __has_builtin(__builtin_amdgcn_cvt_pk_fp8_f32)
    return (unsigned)__builtin_amdgcn_cvt_pk_fp8_f32(a, b, 0, false) & 0xFFFFu;
#else
    __hip_fp8_e4m3 fa(a), fb(b);
    return (unsigned)fa.__x | ((unsigned)fb.__x << 8);
#endif
}

// Gaussian soft bins, anchored geometric recurrence:
//   E_k = exp(-50 (mm - mu_k)^2), mu_k = -0.95 + 0.1k
//   E_{k+1} = E_k * U * e^{-k},   U = e^{10 mm + 9}
// Anchors at k = 0, 7, 14 (spans <= 6 steps). Underflowed anchors only zero
// terms whose true value < 1e-38 -> negligible in Sqk sums.
#define EVAL_BINS(mm, ACC0)                                                  \
    {                                                                        \
        float U  = EXP2F(L2E * fmaf(10.0f, (mm), 9.0f));                     \
        float t0 = (mm) + 0.95f;                                             \
        float E  = EXP2F((-50.0f * L2E) * t0 * t0);                          \
        ACC0[0] += E;                                                        \
        E *= U;                           ACC0[1]  += E; /* e^-0  */         \
        E *= U * 0.36787944117144233f;    ACC0[2]  += E; /* e^-1  */         \
        E *= U * 0.1353352832366127f;     ACC0[3]  += E; /* e^-2  */         \
        E *= U * 0.049787068367863944f;   ACC0[4]  += E; /* e^-3  */         \
        E *= U * 0.018315638888734179f;   ACC0[5]  += E; /* e^-4  */         \
        E *= U * 0.006737946999085467f;   ACC0[6]  += E; /* e^-5  */         \
        float t7 = (mm) + 0.25f;                                             \
        E = EXP2F((-50.0f * L2E) * t7 * t7);                                 \
        ACC0[7] += E;                                                        \
        E *= U * 0.0009118819655545162f;  ACC0[8]  += E; /* e^-7  */         \
        E *= U * 0.00033546262790251185f; ACC0[9]  += E; /* e^-8  */         \
        E *= U * 0.0001234098040866796f;  ACC0[10] += E; /* e^-9  */         \
        E *= U * 4.5399929762484854e-05f; ACC0[11] += E; /* e^-10 */         \
        E *= U * 1.670170079024566e-05f;  ACC0[12] += E; /* e^-11 */         \
        E *= U * 6.14421235332821e-06f;   ACC0[13] += E; /* e^-12 */         \
        float t14 = (mm) - 0.45f;                                            \
        E = EXP2F((-50.0f * L2E) * t14 * t14);                               \
        ACC0[14] += E;                                                       \
        E *= U * 8.315287191035679e-07f;  ACC0[15] += E; /* e^-14 */         \
        E *= U * 3.059023205018258e-07f;  ACC0[16] += E; /* e^-15 */         \
        E *= U * 1.1253517471925912e-07f; ACC0[17] += E; /* e^-16 */         \
        E *= U * 4.139937718785167e-08f;  ACC0[18] += E; /* e^-17 */         \
        E *= U * 1.522997974471263e-08f;  ACC0[19] += E; /* e^-18 */         \
    }

// ---------- Phase 1: normalize emb rows -> fp8 e4m3 table (scaled x16) -------
__global__ __launch_bounds__(256)
void knrm_prep8(const float* __restrict__ emb, unsigned char* __restrict__ tab, int V)
{
    const int wave = threadIdx.x >> 6;
    const int lane = threadIdx.x & 63;
    const int row0 = (blockIdx.x * 4 + wave) * 2;
    if (row0 >= V) return;                     // V even -> row0+1 also valid

    float4 a = reinterpret_cast<const float4*>(emb + (size_t)row0 * DIM)[lane];
    float4 c = reinterpret_cast<const float4*>(emb + (size_t)(row0 + 1) * DIM)[lane];
    float sa = a.x*a.x + a.y*a.y + a.z*a.z + a.w*a.w;
    float sc = c.x*c.x + c.y*c.y + c.z*c.z + c.w*c.w;
    #pragma unroll
    for (int m = 32; m; m >>= 1) { sa += __shfl_xor(sa, m); sc += __shfl_xor(sc, m); }
    float ia = rsqrtf(fmaxf(sa, 1e-16f)) * 16.0f;   // x16 pre-scale
    float ic = rsqrtf(fmaxf(sc, 1e-16f)) * 16.0f;
    unsigned pa = cvt2_e4m3(a.x * ia, a.y * ia) | (cvt2_e4m3(a.z * ia, a.w * ia) << 16);
    unsigned pc = cvt2_e4m3(c.x * ic, c.y * ic) | (cvt2_e4m3(c.z * ic, c.w * ic) << 16);
    *reinterpret_cast<unsigned*>(tab + (size_t)row0 * 256 + lane * 4) = pa;
    *reinterpret_cast<unsigned*>(tab + (size_t)(row0 + 1) * 256 + lane * 4) = pc;
}

// ---------- Phase 2: mainD — best measured configuration (round 9) ----------
// K-permuted dwordx4 gathers: the one lever with a confirmed positive delta
// (mainB 63.6us -> mainD <59.2us). Lane (l31,hw) loads row*256 + j*32 + hw*16
// as dwordx4; call (j,t) uses the t-th 8B half on BOTH operands (exact for a
// dot product). LDS 12.8KB (no residency split); no spill (WRITE ~32B).
// Round-11 lesson: the fused-finale __threadfence costs ~8us (device-scope
// release on non-coherent per-XCD L2s forces L2 writeback x1024 blocks) —
// the separate 4us final launch is cheaper. C layout (verified, shape-
// determined): col=lane&31 (fixed q row -> acc[21] off the fragment),
// row=(reg&3)+8*(reg>>2)+4*(lane>>5).
__global__ __launch_bounds__(256, 2)
void knrm_mainD(const int* __restrict__ q1t, const int* __restrict__ d1t,
                const int* __restrict__ q2t, const int* __restrict__ d2t,
                const unsigned char* __restrict__ tab,
                const float* __restrict__ W0, const float* __restrict__ b0,
                const float* __restrict__ W1, const float* __restrict__ b1,
                const float* __restrict__ W2, const float* __restrict__ b2,
                float* __restrict__ lg, int B)
{
    const int b    = blockIdx.x;
    const int pair = blockIdx.y;
    const int tid  = threadIdx.x;
    const int wave = tid >> 6;
    const int lane = tid & 63;
    const int l31  = lane & 31;    // A row within tile / C col (q row)
    const int hw   = lane >> 5;    // k-slice selector

    const int* qtok = pair ? q2t : q1t;
    const int* dtok = pair ? d2t : d1t;

    __shared__ __align__(16) unsigned char qbuf[QL * STR8];   // 8.5 KB
    __shared__ float Sqk[QL * NK];
    __shared__ int   dtok_s[DL];
    __shared__ float km[NK];
    __shared__ float h0[10];
    __shared__ float h1[5];

    // eval needs the doc tokens; gathers read their own tokens directly.
    dtok_s[tid] = dtok[b * DL + tid];
    for (int e = tid; e < QL * NK; e += 256) Sqk[e] = 0.0f;
    if (tid < NK) km[tid] = 0.0f;

    // ---- issue ALL doc gathers first (tokens direct from global, coalesced)
    const int tok0 = dtok[b * DL + wave * 64 + l31];
    const int tok1 = dtok[b * DL + wave * 64 + 32 + l31];
    const unsigned char* a0 = tab + (size_t)tok0 * 256 + hw * 16;
    const unsigned char* a1 = tab + (size_t)tok1 * 256 + hw * 16;
    i64x2 af0[8], af1[8];
    #pragma unroll
    for (int j = 0; j < 8; ++j)
        af0[j] = *reinterpret_cast<const i64x2*>(a0 + j * 32);
    #pragma unroll
    for (int j = 0; j < 8; ++j)
        af1[j] = *reinterpret_cast<const i64x2*>(a1 + j * 32);

    // ---- stage 32 q rows (coalesced: 2 rows per 8B-lane instr per wave)
    {
        long qv[4];
        #pragma unroll
        for (int i = 0; i < 4; ++i) {
            int r = wave * 8 + i * 2 + hw;
            qv[i] = *reinterpret_cast<const long*>(
                tab + (size_t)qtok[b * QL + r] * 256 + l31 * 8);
        }
        #pragma unroll
        for (int i = 0; i < 4; ++i) {
            int r = wave * 8 + i * 2 + hw;
            *reinterpret_cast<long*>(&qbuf[r * STR8 + l31 * 8]) = qv[i];
        }
    }
    __syncthreads();   // qbuf + dtok_s + Sqk visible; LAST barrier before flush

    const int qtk1 = qtok[b * QL + l31];   // this lane's q token (C col fixed)
    const unsigned char* qrd = &qbuf[l31 * STR8 + hw * 16];

    float acc[NK];
    #pragma unroll
    for (int k = 0; k < NK; ++k) acc[k] = 0.0f;

    // ================= tile 0: docs [wave*64, +32) =================
    {
        f32x16 mc;
        #pragma unroll
        for (int j = 0; j < 16; ++j) mc[j] = 0.0f;
        #pragma unroll
        for (int j = 0; j < 8; ++j) {
            i64x2 qd = *reinterpret_cast<const i64x2*>(qrd + j * 32);
            mc = __builtin_amdgcn_mfma_f32_32x32x16_fp8_fp8(af0[j].x, qd.x, mc, 0, 0, 0);
            mc = __builtin_amdgcn_mfma_f32_32x32x16_fp8_fp8(af0[j].y, qd.y, mc, 0, 0, 0);
        }
        const int dbase = wave * 64;
        #pragma unroll
        for (int r = 0; r < 16; ++r) {
            float mm = mc[r] * 0.00390625f;      // undo x16*x16 scale
            EVAL_BINS(mm, acc);
            int crow = dbase + (r & 3) + 8 * (r >> 2) + 4 * hw;
            acc[KSOFT] += (dtok_s[crow] == qtk1) ? 1.0f : 0.0f;
        }
    }
    // ================= tile 1: docs [wave*64+32, +32) ==============
    {
        f32x16 mc;
        #pragma unroll
        for (int j = 0; j < 16; ++j) mc[j] = 0.0f;
        #pragma unroll
        for (int j = 0; j < 8; ++j) {
            i64x2 qd = *reinterpret_cast<const i64x2*>(qrd + j * 32);
            mc = __builtin_amdgcn_mfma_f32_32x32x16_fp8_fp8(af1[j].x, qd.x, mc, 0, 0, 0);
            mc = __builtin_amdgcn_mfma_f32_32x32x16_fp8_fp8(af1[j].y, qd.y, mc, 0, 0, 0);
        }
        const int dbase = wave * 64 + 32;
        #pragma unroll
        for (int r = 0; r < 16; ++r) {
            float mm = mc[r] * 0.00390625f;
            EVAL_BINS(mm, acc);
            int crow = dbase + (r & 3) + 8 * (r >> 2) + 4 * hw;
            acc[KSOFT] += (dtok_s[crow] == qtk1) ? 1.0f : 0.0f;
        }
    }

    // ---- flush: 8 lanes (2 half-waves x 4 doc-waves) merge per q-row
    #pragma unroll
    for (int k = 0; k < NK; ++k)
        atomicAdd(&Sqk[l31 * NK + k], acc[k]);
    __syncthreads();

    // ---- km[k] = sum_q log1p(Sqk[q][k])
    for (int e = tid; e < QL * NK; e += 256)
        atomicAdd(&km[e % NK], log1pf(Sqk[e]));
    __syncthreads();

    // ---- tiny MLP 21 -> 10 -> 5 -> 1
    if (tid < 10) {
        float h = b0[tid];
        #pragma unroll
        for (int k = 0; k < NK; ++k) h = fmaf(km[k], W0[tid*NK + k], h);
        h0[tid] = fmaxf(h, 0.0f);
    }
    __syncthreads();
    if (tid < 5) {
        float h = b1[tid];
        #pragma unroll
        for (int j = 0; j < 10; ++j) h = fmaf(h0[j], W1[tid*10 + j], h);
        h1[tid] = fmaxf(h, 0.0f);
    }
    __syncthreads();
    if (tid == 0) {
        float l = b2[0];
        #pragma unroll
        for (int j = 0; j < 5; ++j) l = fmaf(h1[j], W2[j], l);
        lg[pair * B + b] = l;
    }
}

__global__ void knrm_final(const float* __restrict__ lg, float* __restrict__ out, int B)
{
    int i = blockIdx.x * 256 + threadIdx.x;
    if (i < B) {
        float z = lg[i] - lg[B + i];
        out[i] = 1.0f / (1.0f + expf(-z));
    }
}

// ---------- Fallback (monolithic): only if ws can't hold the fp8 table -------
__global__ __launch_bounds__(256, 2)
void knrm_mono(const int* __restrict__ q1t, const int* __restrict__ d1t,
               const int* __restrict__ q2t, const int* __restrict__ d2t,
               const float* __restrict__ emb,
               const float* __restrict__ W0, const float* __restrict__ b0,
               const float* __restrict__ W1, const float* __restrict__ b1,
               const float* __restrict__ W2, const float* __restrict__ b2,
               float* __restrict__ out)
{
    const int b    = blockIdx.x;
    const int tid  = threadIdx.x;
    const int wave = tid >> 6;
    const int lane = tid & 63;
    const int qt   = wave >> 1;
    const int dt   = wave & 1;
    const int g    = lane >> 4;
    const int cl   = lane & 15;

    __shared__ __align__(16) __bf16 qbuf[QL * STR];
    __shared__ __align__(16) __bf16 dbuf[32 * STR];
    __shared__ float Sqk[QL * NK];
    __shared__ int   dtok_s[DL];
    __shared__ int   qtok_s[QL];
    __shared__ float km[NK];
    __shared__ float h0[10];
    __shared__ float h1[5];
    __shared__ float logit[2];

    for (int pair = 0; pair < 2; ++pair) {
        const int* qtok = pair ? q2t : q1t;
        const int* dtok = pair ? d2t : d1t;

        if (tid < QL) qtok_s[tid] = qtok[b * QL + tid];
        dtok_s[tid] = dtok[b * DL + tid];
        for (int e = tid; e < QL * NK; e += 256) Sqk[e] = 0.0f;
        if (tid < NK) km[tid] = 0.0f;
        __syncthreads();

        #pragma unroll
        for (int i = 0; i < 8; ++i) {
            int row = wave * 8 + i;
            int tok = qtok_s[row];
            float4 v = reinterpret_cast<const float4*>(emb + (size_t)tok * DIM)[lane];
            float s = v.x*v.x + v.y*v.y + v.z*v.z + v.w*v.w;
            #pragma unroll
            for (int m = 32; m; m >>= 1) s += __shfl_xor(s, m);
            float inv = rsqrtf(fmaxf(s, 1e-16f));
            bf16x4 o;
            o[0] = (__bf16)(v.x * inv); o[1] = (__bf16)(v.y * inv);
            o[2] = (__bf16)(v.z * inv); o[3] = (__bf16)(v.w * inv);
            *reinterpret_cast<bf16x4*>(&qbuf[row * STR + lane * 4]) = o;
        }

        int qtk[4];
        #pragma unroll
        for (int i = 0; i < 4; ++i) qtk[i] = qtok_s[qt * 16 + g * 4 + i];

        float acc[4 * NK];
        #pragma unroll
        for (int e = 0; e < 4 * NK; ++e) acc[e] = 0.0f;

        for (int tile = 0; tile < 8; ++tile) {
            #pragma unroll
            for (int i = 0; i < 8; ++i) {
                int r = wave * 8 + i;
                int tok = dtok_s[tile * 32 + r];
                float4 v = reinterpret_cast<const float4*>(emb + (size_t)tok * DIM)[lane];
                float s = v.x*v.x + v.y*v.y + v.z*v.z + v.w*v.w;
                #pragma unroll
                for (int m = 32; m; m >>= 1) s += __shfl_xor(s, m);
                float inv = rsqrtf(fmaxf(s, 1e-16f));
                bf16x4 o;
                o[0] = (__bf16)(v.x * inv); o[1] = (__bf16)(v.y * inv);
                o[2] = (__bf16)(v.z * inv); o[3] = (__bf16)(v.w * inv);
                *reinterpret_cast<bf16x4*>(&dbuf[r * STR + lane * 4]) = o;
            }
            __syncthreads();

            f32x4 cf = {0.0f, 0.0f, 0.0f, 0.0f};
            #pragma unroll
            for (int ks = 0; ks < 8; ++ks) {
                bf16x8 af  = *reinterpret_cast<const bf16x8*>(&qbuf[(qt*16 + cl)*STR + ks*32 + g*8]);
                bf16x8 bfr = *reinterpret_cast<const bf16x8*>(&dbuf[(dt*16 + cl)*STR + ks*32 + g*8]);
                cf = __builtin_amdgcn_mfma_f32_16x16x32_bf16(af, bfr, cf, 0, 0, 0);
            }

            int dtk = dtok_s[tile*32 + dt*16 + cl];
            #pragma unroll
            for (int i = 0; i < 4; ++i) {
                float mm = cf[i];
                float* a4 = &acc[i*NK];
                EVAL_BINS(mm, a4);
                a4[KSOFT] += (dtk == qtk[i]) ? 1.0f : 0.0f;
            }
            __syncthreads();
        }

        #pragma unroll
        for (int i = 0; i < 4; ++i) {
            int row = qt*16 + g*4 + i;
            #pragma unroll
            for (int k = 0; k < NK; ++k)
                atomicAdd(&Sqk[row*NK + k], acc[i*NK + k]);
        }
        __syncthreads();

        for (int e = tid; e < QL * NK; e += 256)
            atomicAdd(&km[e % NK], log1pf(Sqk[e]));
        __syncthreads();

        if (tid < 10) {
            float h = b0[tid];
            #pragma unroll
            for (int k = 0; k < NK; ++k) h = fmaf(km[k], W0[tid*NK + k], h);
            h0[tid] = fmaxf(h, 0.0f);
        }
        __syncthreads();
        if (tid < 5) {
            float h = b1[tid];
            #pragma unroll
            for (int j = 0; j < 10; ++j) h = fmaf(h0[j], W1[tid*10 + j], h);
            h1[tid] = fmaxf(h, 0.0f);
        }
        __syncthreads();
        if (tid == 0) {
            float l = b2[0];
            #pragma unroll
            for (int j = 0; j < 5; ++j) l = fmaf(h1[j], W2[j], l);
            logit[pair] = l;
        }
        __syncthreads();
    }

    if (tid == 0) {
        float z = logit[0] - logit[1];
        out[b] = 1.0f / (1.0f + expf(-z));
    }
}

extern "C" void kernel_launch(void* const* d_in, const int* in_sizes, int n_in,
                              void* d_out, int out_size, void* d_ws, size_t ws_size,
                              hipStream_t stream) {
    const int*   q1  = (const int*)d_in[0];
    const int*   d1  = (const int*)d_in[1];
    const int*   q2  = (const int*)d_in[2];
    const int*   d2  = (const int*)d_in[3];
    const float* emb = (const float*)d_in[4];
    const float* W0  = (const float*)d_in[5];
    const float* b0  = (const float*)d_in[6];
    const float* W1  = (const float*)d_in[7];
    const float* b1  = (const float*)d_in[8];
    const float* W2  = (const float*)d_in[9];
    const float* b2  = (const float*)d_in[10];
    float* out = (float*)d_out;

    const int B = in_sizes[0] / QL;       // 512
    const int V = in_sizes[4] / DIM;      // 100000

    size_t tab_bytes = (size_t)V * 256;   // fp8 table
    size_t need = tab_bytes + 256 + (size_t)2 * B * sizeof(float);

    if (ws_size >= need) {
        unsigned char* tab = (unsigned char*)d_ws;
        float* lg = (float*)((char*)d_ws + ((tab_bytes + 255) & ~(size_t)255));

        knrm_prep8<<<(V/2 + 3) / 4, 256, 0, stream>>>(emb, tab, V);
        dim3 grid(B, 2);
        knrm_mainD<<<grid, 256, 0, stream>>>(q1, d1, q2, d2, tab,
                                             W0, b0, W1, b1, W2, b2, lg, B);
        knrm_final<<<(B + 255) / 256, 256, 0, stream>>>(lg, out, B);
    } else {
        knrm_mono<<<B, 256, 0, stream>>>(q1, d1, q2, d2, emb,
                                         W0, b0, W1, b1, W2, b2, out);
    }
}